// Round 2
// baseline (452.947 us; speedup 1.0000x reference)
//
#include <hip/hip_runtime.h>

// EMA: y[0]=x[0]; y[t] = s*x[t] + (1-s)*y[t-1], s=0.3, (B,T,D)=(64,4096,256) f32.
// Constant decay 0.7 => chunks along T are independent after a 32-step warm-up
// (0.7^32 ~ 1.1e-5 relative carry error, far under the 7.8e-3 tolerance).
//
// v2 changes vs the 443us float2/L=256 kernel (theory: latency-bound at
// 2 waves/SIMD with only ~4KB in-flight per wave):
//   - float4-width lanes (native clang ext_vector so nontemporal builtins
//     accept it): 16B/lane, 1KiB per wave-load, half the VMEM instructions,
//     2x in-flight bytes at the same unroll depth.
//   - L=128 (NC=32): keeps 131072 threads / 512 blocks at float4 width.
//     Warm-up read overhead 25% (+32MiB, ~5us at the BW floor) -- acceptable.
//   - Non-temporal stores for y (write-once stream; keep L2 for x tails).
//   - XCD-aware bijective block swizzle: 64 consecutive logical blocks
//     (= 8 whole batches) per XCD, so warm-up re-reads of chunk tails stay
//     on-XCD and can hit that XCD's L2.
// Memory floor: 256MiB*1.25 read + 256MiB write = 576MiB ~ 91us @ 6.3TB/s.

typedef float f32x4 __attribute__((ext_vector_type(4)));

constexpr int   Bc = 64;
constexpr int   Tc = 4096;
constexpr int   Dc = 256;
constexpr float S  = 0.3f;
constexpr float R  = 1.0f - S;

constexpr int L  = 128;        // chunk length along T
constexpr int W  = 32;         // warm-up steps (0.7^33 ~ 7e-6 relative error)
constexpr int DQ = Dc / 4;     // 64 f32x4 per (b,t) row
constexpr int NC = Tc / L;     // 32 chunks

__global__ __launch_bounds__(256)
void ema_f32_kernel(const f32x4* __restrict__ x,
                    f32x4* __restrict__ y)
{
    // XCD swizzle: 512 blocks, 8 XCDs, 64 blocks/XCD. HW round-robins
    // blockIdx%8 across XCDs; remap so one XCD owns 64 consecutive logical
    // blocks = 8 complete batches (all warm-up re-reads on-XCD).
    // 512 % 8 == 0 so this is bijective.
    const int cpx = gridDim.x >> 3;                       // 64
    const int lb  = (blockIdx.x & 7) * cpx + (blockIdx.x >> 3);

    const int tid = lb * 256 + (int)threadIdx.x;
    const int dq  = tid & (DQ - 1);          // f32x4 index in row    [0,64)
    const int c   = (tid >> 6) & (NC - 1);   // chunk index           [0,32)
    const int b   = tid >> 11;               // batch index           [0,64)
    const int t0  = c * L;
    const int base = b * (Tc * DQ) + dq;     // f32x4-element index at t=0
                                             // max 16.7M < 2^31: int math ok

    float y0 = 0.f, y1 = 0.f, y2 = 0.f, y3 = 0.f;
    int tstart = t0;

    if (c == 0) {
        // exact init: y[0] = x[0]
        f32x4 v = x[base];
        y0 = v.x; y1 = v.y; y2 = v.z; y3 = v.w;
        __builtin_nontemporal_store(v, &y[base]);
        tstart = 1;
    } else {
        // warm-up from zero init, W steps before the chunk (loads only)
        #pragma unroll 8
        for (int t = t0 - W; t < t0; ++t) {
            f32x4 v = x[base + t * DQ];
            y0 = fmaf(R, y0, S * v.x);
            y1 = fmaf(R, y1, S * v.y);
            y2 = fmaf(R, y2, S * v.z);
            y3 = fmaf(R, y3, S * v.w);
        }
    }

    #pragma unroll 8
    for (int t = tstart; t < t0 + L; ++t) {
        f32x4 v = x[base + t * DQ];
        y0 = fmaf(R, y0, S * v.x);
        y1 = fmaf(R, y1, S * v.y);
        y2 = fmaf(R, y2, S * v.z);
        y3 = fmaf(R, y3, S * v.w);
        f32x4 o;
        o.x = y0; o.y = y1; o.z = y2; o.w = y3;
        __builtin_nontemporal_store(o, &y[base + t * DQ]);
    }
}

extern "C" void kernel_launch(void* const* d_in, const int* in_sizes, int n_in,
                              void* d_out, int out_size, void* d_ws, size_t ws_size,
                              hipStream_t stream) {
    (void)in_sizes; (void)n_in; (void)d_ws; (void)ws_size; (void)out_size;
    const f32x4* x = (const f32x4*)d_in[0];
    f32x4*       y = (f32x4*)d_out;

    const int total_threads = Bc * NC * DQ;     // 64*32*64 = 131072
    dim3 grid(total_threads / 256), block(256); // 512 blocks
    hipLaunchKernelGGL(ema_f32_kernel, grid, block, 0, stream, x, y);
}

// Round 3
// 449.036 us; speedup vs baseline: 1.0087x; 1.0087x over previous
//
#include <hip/hip_runtime.h>

// EMA: y[0]=x[0]; y[t] = s*x[t] + (1-s)*y[t-1], s=0.3, (B,T,D)=(64,4096,256) f32.
// Constant decay 0.7 => chunks along T are independent after a short warm-up.
// W=24: carry error 0.7^24 * |y|max ~ 5e-4, tolerance 7.8e-3.
//
// v3 (post-mortem of v2: 165us @ 2.6 TB/s, VGPR=36, Occ=19% -> latency-bound
// on BOTH axes: only 2 waves/SIMD and ~2 loads in flight per wave):
//   - TLP: L=64 -> NC=64 -> 1024 blocks = 4 blocks/CU = 16 waves/CU.
//   - ILP: explicit 8-deep register prefetch pipeline (load group g+1 into
//     nxt[8] BEFORE computing group g; fully unrolled, static indices only).
//     Forces ~64 VGPRs of load buffer => ~8KB in flight per wave, and loads
//     issue ahead of the store stream instead of behind it.
//   - Uniform chunk code: c==0 seeds y_init = x[0] (0.3*x0+0.7*x0 == x0),
//     so all chunks run the same 64-step pipelined loop.
// Traffic: reads 256MiB*(1+24/64)=368MB nominal (L3 absorbs part; v2 showed
// FETCH 163MB vs 268MB nominal), writes 268MB. Floor ~(368+268)/6.3 ~ 101us.

typedef float f32x4 __attribute__((ext_vector_type(4)));

constexpr int   Bc = 64;
constexpr int   Tc = 4096;
constexpr int   Dc = 256;
constexpr float S  = 0.3f;
constexpr float R  = 1.0f - S;

constexpr int L  = 64;         // chunk length along T
constexpr int W  = 24;         // warm-up steps
constexpr int DQ = Dc / 4;     // 64 f32x4 per (b,t) row
constexpr int NC = Tc / L;     // 64 chunks
constexpr int G  = 8;          // pipeline group (timesteps)
constexpr int NG = L / G;      // 8 groups

__global__ __launch_bounds__(256)
void ema_f32_kernel(const f32x4* __restrict__ x,
                    f32x4* __restrict__ y)
{
    // XCD swizzle: 1024 blocks, 8 XCDs, 128 consecutive logical blocks per
    // XCD (bijective since 1024 % 8 == 0). Warm-up re-reads stay on-XCD.
    const int cpx = gridDim.x >> 3;                       // 128
    const int lb  = ((int)blockIdx.x & 7) * cpx + ((int)blockIdx.x >> 3);

    const int tid = lb * 256 + (int)threadIdx.x;
    const int dq  = tid & (DQ - 1);          // f32x4 index in row    [0,64)
    const int c   = (tid >> 6) & (NC - 1);   // chunk index           [0,64)
    const int b   = tid >> 12;               // batch index           [0,64)
    const int t0  = c * L;
    const int base = b * (Tc * DQ) + dq;     // f32x4 elem index at t=0 (<2^25)

    float y0, y1, y2, y3;

    if (c == 0) {
        // Seed so that step t=0 reproduces y[0]=x[0]: 0.3*x0 + 0.7*x0 = x0.
        f32x4 v = x[base];
        y0 = v.x; y1 = v.y; y2 = v.z; y3 = v.w;
    } else {
        // Warm-up from zero init, W steps before the chunk (loads only).
        y0 = 0.f; y1 = 0.f; y2 = 0.f; y3 = 0.f;
        const f32x4* __restrict__ wp = x + base + (t0 - W) * DQ;
        #pragma unroll
        for (int t = 0; t < W; ++t) {
            f32x4 v = wp[t * DQ];
            y0 = fmaf(R, y0, S * v.x);
            y1 = fmaf(R, y1, S * v.y);
            y2 = fmaf(R, y2, S * v.z);
            y3 = fmaf(R, y3, S * v.w);
        }
    }

    // Main chunk: 8-deep register prefetch pipeline, fully unrolled.
    const f32x4* __restrict__ xp = x + base + t0 * DQ;
    f32x4*       __restrict__ yp = y + base + t0 * DQ;

    f32x4 cur[G];
    #pragma unroll
    for (int i = 0; i < G; ++i) cur[i] = xp[i * DQ];

    #pragma unroll
    for (int g = 0; g < NG; ++g) {
        f32x4 nxt[G];
        if (g + 1 < NG) {
            #pragma unroll
            for (int i = 0; i < G; ++i) nxt[i] = xp[((g + 1) * G + i) * DQ];
        }
        #pragma unroll
        for (int i = 0; i < G; ++i) {
            y0 = fmaf(R, y0, S * cur[i].x);
            y1 = fmaf(R, y1, S * cur[i].y);
            y2 = fmaf(R, y2, S * cur[i].z);
            y3 = fmaf(R, y3, S * cur[i].w);
            f32x4 o;
            o.x = y0; o.y = y1; o.z = y2; o.w = y3;
            __builtin_nontemporal_store(o, &yp[(g * G + i) * DQ]);
        }
        #pragma unroll
        for (int i = 0; i < G; ++i) cur[i] = nxt[i];
    }
}

extern "C" void kernel_launch(void* const* d_in, const int* in_sizes, int n_in,
                              void* d_out, int out_size, void* d_ws, size_t ws_size,
                              hipStream_t stream) {
    (void)in_sizes; (void)n_in; (void)d_ws; (void)ws_size; (void)out_size;
    const f32x4* x = (const f32x4*)d_in[0];
    f32x4*       y = (f32x4*)d_out;

    const int total_threads = Bc * NC * DQ;     // 64*64*64 = 262144
    dim3 grid(total_threads / 256), block(256); // 1024 blocks
    hipLaunchKernelGGL(ema_f32_kernel, grid, block, 0, stream, x, y);
}

// Round 4
// 441.310 us; speedup vs baseline: 1.0264x; 1.0175x over previous
//
#include <hip/hip_runtime.h>

// EMA: y[0]=x[0]; y[t] = s*x[t] + (1-s)*y[t-1], s=0.3, (B,T,D)=(64,4096,256) f32.
// Constant decay 0.7 => chunks along T are independent after a short warm-up.
// W=24: carry error 0.7^24 * |y| ~ 2e-3 worst case, tolerance 7.8e-3.
//
// v4 (post-mortem of v3: harness dur flat at ~449 despite 2x TLP + 8-deep
// pipeline => kernel pinned at ~160us / ~3.4 TB/s program-side while the
// same-mix float4 copy ubench does 6.3 TB/s. The one memory-path difference
// vs a copy: NONTEMPORAL stores, introduced in v2 and kept since. Theory:
// nt bypasses L2 write-combining and caps store drain; stores share vmcnt
// with loads, so store-drain gates the loop regardless of occupancy/ILP --
// exactly the observed insensitivity):
//   - PLAIN stores (y streams through L2, like the 6.3 TB/s fill kernel).
//   - keep v3 structure: L=64 -> 1024 blocks = 4 blocks/CU = 16 waves/CU,
//     8-deep register prefetch pipeline, uniform chunk code, XCD swizzle.
//   - __launch_bounds__(256,4): guarantee 4 blocks/CU residency (VGPR<=128).
// Traffic: reads 256MiB*(1+24/64)=368MB nominal (L3 absorbed ~40% in v2),
// writes 268MB. Floor ~(368+268)/6.3 ~ 101us; ~85us if L3 absorption holds.

typedef float f32x4 __attribute__((ext_vector_type(4)));

constexpr int   Bc = 64;
constexpr int   Tc = 4096;
constexpr int   Dc = 256;
constexpr float S  = 0.3f;
constexpr float R  = 1.0f - S;

constexpr int L  = 64;         // chunk length along T
constexpr int W  = 24;         // warm-up steps
constexpr int DQ = Dc / 4;     // 64 f32x4 per (b,t) row
constexpr int NC = Tc / L;     // 64 chunks
constexpr int G  = 8;          // pipeline group (timesteps)
constexpr int NG = L / G;      // 8 groups

__global__ __launch_bounds__(256, 4)
void ema_f32_kernel(const f32x4* __restrict__ x,
                    f32x4* __restrict__ y)
{
    // XCD swizzle: 1024 blocks, 8 XCDs, 128 consecutive logical blocks per
    // XCD (bijective since 1024 % 8 == 0). Warm-up re-reads stay on-XCD.
    const int cpx = gridDim.x >> 3;                       // 128
    const int lb  = ((int)blockIdx.x & 7) * cpx + ((int)blockIdx.x >> 3);

    const int tid = lb * 256 + (int)threadIdx.x;
    const int dq  = tid & (DQ - 1);          // f32x4 index in row    [0,64)
    const int c   = (tid >> 6) & (NC - 1);   // chunk index           [0,64)
    const int b   = tid >> 12;               // batch index           [0,64)
    const int t0  = c * L;
    const int base = b * (Tc * DQ) + dq;     // f32x4 elem index at t=0 (<2^25)

    float y0, y1, y2, y3;

    if (c == 0) {
        // Seed so that step t=0 reproduces y[0]=x[0]: 0.3*x0 + 0.7*x0 = x0.
        f32x4 v = x[base];
        y0 = v.x; y1 = v.y; y2 = v.z; y3 = v.w;
    } else {
        // Warm-up from zero init, W steps before the chunk (loads only).
        y0 = 0.f; y1 = 0.f; y2 = 0.f; y3 = 0.f;
        const f32x4* __restrict__ wp = x + base + (t0 - W) * DQ;
        #pragma unroll
        for (int t = 0; t < W; ++t) {
            f32x4 v = wp[t * DQ];
            y0 = fmaf(R, y0, S * v.x);
            y1 = fmaf(R, y1, S * v.y);
            y2 = fmaf(R, y2, S * v.z);
            y3 = fmaf(R, y3, S * v.w);
        }
    }

    // Main chunk: 8-deep register prefetch pipeline, fully unrolled.
    const f32x4* __restrict__ xp = x + base + t0 * DQ;
    f32x4*       __restrict__ yp = y + base + t0 * DQ;

    f32x4 cur[G];
    #pragma unroll
    for (int i = 0; i < G; ++i) cur[i] = xp[i * DQ];

    #pragma unroll
    for (int g = 0; g < NG; ++g) {
        f32x4 nxt[G];
        if (g + 1 < NG) {
            #pragma unroll
            for (int i = 0; i < G; ++i) nxt[i] = xp[((g + 1) * G + i) * DQ];
        }
        #pragma unroll
        for (int i = 0; i < G; ++i) {
            y0 = fmaf(R, y0, S * cur[i].x);
            y1 = fmaf(R, y1, S * cur[i].y);
            y2 = fmaf(R, y2, S * cur[i].z);
            y3 = fmaf(R, y3, S * cur[i].w);
            f32x4 o;
            o.x = y0; o.y = y1; o.z = y2; o.w = y3;
            yp[(g * G + i) * DQ] = o;   // plain store: stream through L2
        }
        #pragma unroll
        for (int i = 0; i < G; ++i) cur[i] = nxt[i];
    }
}

extern "C" void kernel_launch(void* const* d_in, const int* in_sizes, int n_in,
                              void* d_out, int out_size, void* d_ws, size_t ws_size,
                              hipStream_t stream) {
    (void)in_sizes; (void)n_in; (void)d_ws; (void)ws_size; (void)out_size;
    const f32x4* x = (const f32x4*)d_in[0];
    f32x4*       y = (f32x4*)d_out;

    const int total_threads = Bc * NC * DQ;     // 64*64*64 = 262144
    dim3 grid(total_threads / 256), block(256); // 1024 blocks
    hipLaunchKernelGGL(ema_f32_kernel, grid, block, 0, stream, x, y);
}